// Round 7
// baseline (210.646 us; speedup 1.0000x reference)
//
#include <hip/hip_runtime.h>
#include <math.h>

// Problem constants (B=2, T=2048, E=1024, H=16, S=64)
#define T_SEQ 2048
#define E_DIM 1024
#define NH    16
#define HS    64
#define NB    2
#define M_ROWS 4096

typedef __attribute__((ext_vector_type(8))) short bf16x8;
typedef __attribute__((ext_vector_type(4))) short bf16x4;
typedef __attribute__((ext_vector_type(4))) float f32x4;

#define AS1 __attribute__((address_space(1)))
#define AS3 __attribute__((address_space(3)))

#define LOG2E 1.4426950408889634f

// 16x16x16 bf16 MFMA (K=16): B-operand k-index (quad*4+j) matches the
// C-layout row index (quad*4+r) — QK^T's S^T accumulator feeds PV directly.
__device__ __forceinline__ f32x4 mfma16(bf16x4 a, bf16x4 b, f32x4 c) {
    return __builtin_amdgcn_mfma_f32_16x16x16bf16_1k(a, b, c, 0, 0, 0);
}

__device__ __forceinline__ ushort f2bf(float f) {
    union { float f; unsigned u; } c; c.f = f;
    unsigned r = c.u + 0x7fffu + ((c.u >> 16) & 1u);
    return (ushort)(r >> 16);
}
__device__ __forceinline__ ushort f2bf_trunc(float f) {
    union { float f; unsigned u; } c; c.f = f;
    return (ushort)(c.u >> 16);
}

__device__ __forceinline__ void load_lds16(const ushort* g, ushort* l) {
    // 16B per lane, LDS dest = wave-uniform base + lane*16 (HW behavior)
    __builtin_amdgcn_global_load_lds((const AS1 unsigned int*)g,
                                     (AS3 unsigned int*)l, 16, 0, 0);
}

// ---------------------------------------------------------------------------
// fp32 -> bf16 conversion for x and the four weight matrices.
// ---------------------------------------------------------------------------
__global__ __launch_bounds__(256) void cvt_all(
    const float* __restrict__ x,  const float* __restrict__ Wk,
    const float* __restrict__ Wq, const float* __restrict__ Wv,
    const float* __restrict__ Wu,
    ushort* __restrict__ xb,  ushort* __restrict__ Wkb,
    ushort* __restrict__ Wqb, ushort* __restrict__ Wvb,
    ushort* __restrict__ Wub)
{
    int i4 = blockIdx.x * 256 + threadIdx.x;   // 0 .. 2M-1 (float4 units)
    int region = i4 >> 18;
    const float* src; ushort* dst; int off;
    if      (region < 4)  { src = x;  dst = xb;  off = i4; }
    else if (region == 4) { src = Wk; dst = Wkb; off = i4 - (4 << 18); }
    else if (region == 5) { src = Wq; dst = Wqb; off = i4 - (5 << 18); }
    else if (region == 6) { src = Wv; dst = Wvb; off = i4 - (6 << 18); }
    else                  { src = Wu; dst = Wub; off = i4 - (7 << 18); }
    float4 v = *(const float4*)(src + (size_t)off * 4);
    ushort4 o; o.x = f2bf(v.x); o.y = f2bf(v.y); o.z = f2bf(v.z); o.w = f2bf(v.w);
    *(ushort4*)(dst + (size_t)off * 4) = o;
}

// ---------------------------------------------------------------------------
// bf16 MFMA GEMM core, 128x128 tile, BK=32, 4 waves, double-buffered.
// 32 KB LDS -> 3+ blocks/CU; inter-block overlap hides the per-tile drains.
// (Measured: ties or beats every fancier schedule tried on this problem.)
// ---------------------------------------------------------------------------
__device__ __forceinline__ void gemm_core_db(
    const ushort* __restrict__ A, const ushort* __restrict__ W,
    int m0, int n0, ushort* As, ushort* Bs, f32x4 acc[4][4])
{
    const int tid  = threadIdx.x;
    const int lane = tid & 63, w = tid >> 6;
    const int quad = lane >> 4, l16 = lane & 15;
    const int wm = w & 1, wn = w >> 1;

    const int rl   = lane >> 2;                       // row-in-chunk 0..15
    const int gsw  = (lane & 3) ^ ((lane >> 3) & 3);  // swizzled global chunk
    const int fsw  = (l16 >> 1) & 3;                  // frag-read xor factor

    const f32x4 zero = {0.f, 0.f, 0.f, 0.f};
#pragma unroll
    for (int mt = 0; mt < 4; ++mt)
#pragma unroll
        for (int nt = 0; nt < 4; ++nt) acc[mt][nt] = zero;

    // initial stage into buffer 0
#pragma unroll
    for (int i = 0; i < 2; ++i) {
        int c = i * 4 + w;                 // chunk 0..7 (16 rows x 64B)
        int row = c * 16 + rl;
        load_lds16(A + (size_t)(m0 + row) * E_DIM + gsw * 8, As + c * 512);
        load_lds16(W + (size_t)(n0 + row) * E_DIM + gsw * 8, Bs + c * 512);
    }

    for (int k0 = 0; k0 < E_DIM; k0 += 32) {
        const int buf = (k0 >> 5) & 1;
        ushort* Ab = As + buf * 4096;
        ushort* Bb = Bs + buf * 4096;
        __syncthreads();   // own-wave vmcnt drained -> buf ready; syncs reuse
        if (k0 + 32 < E_DIM) {
            ushort* An = As + (buf ^ 1) * 4096;
            ushort* Bn = Bs + (buf ^ 1) * 4096;
#pragma unroll
            for (int i = 0; i < 2; ++i) {
                int c = i * 4 + w;
                int row = c * 16 + rl;
                load_lds16(A + (size_t)(m0 + row) * E_DIM + k0 + 32 + gsw * 8,
                           An + c * 512);
                load_lds16(W + (size_t)(n0 + row) * E_DIM + k0 + 32 + gsw * 8,
                           Bn + c * 512);
            }
        }
        bf16x8 af[4], bfr[4];
#pragma unroll
        for (int mt = 0; mt < 4; ++mt)
            af[mt] = *(const bf16x8*)(Ab + (wm * 64 + mt * 16 + l16) * 32
                                      + ((quad ^ fsw) * 8));
#pragma unroll
        for (int nt = 0; nt < 4; ++nt)
            bfr[nt] = *(const bf16x8*)(Bb + (wn * 64 + nt * 16 + l16) * 32
                                       + ((quad ^ fsw) * 8));
#pragma unroll
        for (int mt = 0; mt < 4; ++mt)
#pragma unroll
            for (int nt = 0; nt < 4; ++nt)
                acc[mt][nt] = __builtin_amdgcn_mfma_f32_16x16x32_bf16(
                    af[mt], bfr[nt], acc[mt][nt], 0, 0, 0);
    }
}

// ---------------------------------------------------------------------------
// QKV GEMM (z-grid) with fused epilogues:
//  z=0: K -> LN(kln) -> Kb ; z=1: Q -> LN(qln)*0.125*log2e -> Qb
//  z=2: V -> transposed store -> Vt [bh][d][t]
// ---------------------------------------------------------------------------
__global__ __launch_bounds__(256) void gemm_qkv(
    const ushort* __restrict__ A,
    const ushort* __restrict__ W0, const ushort* __restrict__ W1,
    const ushort* __restrict__ W2,
    ushort* __restrict__ Kb, ushort* __restrict__ Qb, ushort* __restrict__ Vt,
    const float* __restrict__ kw, const float* __restrict__ kbias,
    const float* __restrict__ qw, const float* __restrict__ qbias)
{
    __shared__ ushort As[2 * 128 * 32];   // 16 KB
    __shared__ ushort Bs[2 * 128 * 32];   // 16 KB
    const int z = blockIdx.z;
    const ushort* W = (z == 0) ? W0 : (z == 1) ? W1 : W2;
    const int m0 = blockIdx.y * 128, n0 = blockIdx.x * 128;
    f32x4 acc[4][4];
    gemm_core_db(A, W, m0, n0, As, Bs, acc);

    const int lane = threadIdx.x & 63, w = threadIdx.x >> 6;
    const int quad = lane >> 4, l16 = lane & 15;
    const int wm = w & 1, wn = w >> 1;
    const int row0 = m0 + wm * 64;
    const int col0 = n0 + wn * 64;

    if (z < 2) {
        ushort* C = z ? Qb : Kb;
        const float* lw = z ? qw : kw;
        const float* lb = z ? qbias : kbias;
        const float scale = z ? (0.125f * LOG2E) : 1.0f;
        float wv[4], bv_[4];
#pragma unroll
        for (int nt = 0; nt < 4; ++nt) {
            wv[nt]  = lw[nt * 16 + l16];
            bv_[nt] = lb[nt * 16 + l16];
        }
#pragma unroll
        for (int mt = 0; mt < 4; ++mt)
#pragma unroll
            for (int r = 0; r < 4; ++r) {
                float v[4], d[4];
#pragma unroll
                for (int nt = 0; nt < 4; ++nt) v[nt] = acc[mt][nt][r];
                float s = v[0] + v[1] + v[2] + v[3];
                s += __shfl_xor(s, 1); s += __shfl_xor(s, 2);
                s += __shfl_xor(s, 4); s += __shfl_xor(s, 8);
                float mu = s * (1.0f / 64.0f);
                float q2 = 0.f;
#pragma unroll
                for (int nt = 0; nt < 4; ++nt) { d[nt] = v[nt] - mu; q2 += d[nt] * d[nt]; }
                q2 += __shfl_xor(q2, 1); q2 += __shfl_xor(q2, 2);
                q2 += __shfl_xor(q2, 4); q2 += __shfl_xor(q2, 8);
                float rin = rsqrtf(q2 * (1.0f / 64.0f) + 1e-5f);
                int row = row0 + mt * 16 + quad * 4 + r;
#pragma unroll
                for (int nt = 0; nt < 4; ++nt)
                    C[(size_t)row * E_DIM + col0 + nt * 16 + l16] =
                        f2bf((d[nt] * rin * wv[nt] + bv_[nt]) * scale);
            }
    } else {
        // V: transposed store Vt[(b*NH+h)*64 + d][t]
        const int bidx = m0 >> 11;
        const int hh   = col0 >> 6;
        const int t0   = (m0 & 2047) + wm * 64;
#pragma unroll
        for (int mt = 0; mt < 4; ++mt)
#pragma unroll
            for (int nt = 0; nt < 4; ++nt) {
                ushort4 pk = make_ushort4(f2bf(acc[mt][nt][0]), f2bf(acc[mt][nt][1]),
                                          f2bf(acc[mt][nt][2]), f2bf(acc[mt][nt][3]));
                size_t off = ((size_t)(bidx * NH + hh) * 64 + nt * 16 + l16) * T_SEQ
                             + t0 + mt * 16 + quad * 4;
                *(ushort4*)(Vt + off) = pk;
            }
    }
}

// ---------------------------------------------------------------------------
// Flash attention v6: SPLIT-K causal flash (fixed-max exp2 softmax => exact
// additive partials). Writes un-normalized f32 O^T partials + partial l; the
// merge is fused into gemm_o_m's A-staging (NOT a device-fence protocol —
// the kernel-launch boundary is the cheap device-wide fence).
// Grid 2048 LPT-ordered; (256,5) -> 5 blocks/CU for backfill.
// ---------------------------------------------------------------------------
__global__ __launch_bounds__(256, 5) void flash_attn6(
    const ushort* __restrict__ Qg, const ushort* __restrict__ Kg,
    const ushort* __restrict__ Vt, float* __restrict__ Pbuf,
    float* __restrict__ Lbuf)
{
    __shared__ ushort Ks[2][64 * 64];   // 16 KB
    __shared__ ushort Vs[2][64 * 64];   // 16 KB

    const int tid  = threadIdx.x;
    const int lane = tid & 63, w = tid >> 6;
    const int quad = lane >> 4, l16 = lane & 15;

    const int pair  = blockIdx.x >> 1;          // 0..1023
    const int split = blockIdx.x & 1;
    const int bh = pair & 31;
    const int qt = 31 - (pair >> 5);            // longest work first (LPT)
    const int b = bh >> 4, h = bh & 15;

    const int ntile = qt + 1;
    const int hmid  = ntile >> 1;               // split0: [0,hmid) split1: [hmid,ntile)
    const int jt0 = split ? hmid  : 0;
    const int jt1 = split ? ntile : hmid;
    if (jt0 >= jt1) return;                     // qt=0 split0: empty (uniform)

    const int slot = (bh << 5) | qt;

    const ushort* Qbase = Qg + ((size_t)b * T_SEQ) * E_DIM + h * HS;
    const ushort* Kbase = Kg + ((size_t)b * T_SEQ) * E_DIM + h * HS;
    const ushort* Vbase = Vt + ((size_t)bh * HS) * T_SEQ;   // [d][t]

    const int rloc = lane >> 3;
    const int gswc = (lane & 7) ^ rloc;     // swizzled global chunk (staging)
    const int sw   = l16 & 7;               // frag-read xor factor

    // Q B-frags (16x16x32): B[n=q][k=d], lane n=l16 -> q row, k=quad*8+j
    bf16x8 aq[2];
#pragma unroll
    for (int ks = 0; ks < 2; ++ks)
        aq[ks] = *(const bf16x8*)(Qbase + (size_t)(qt * 64 + w * 16 + l16) * E_DIM
                                  + ks * 32 + quad * 8);

    const f32x4 zero = {0.f, 0.f, 0.f, 0.f};
    f32x4 o_acc[4];                     // O^T: lane col=q(l16), rows d=quad*4+r
#pragma unroll
    for (int dt = 0; dt < 4; ++dt) o_acc[dt] = zero;
    float l_acc = 0.f;                  // q is lane-fixed -> scalar l

    // initial stage of tile jt0 into buffer 0
#pragma unroll
    for (int i = 0; i < 2; ++i) {
        int cc = w * 2 + i, row = cc * 8 + rloc;
        load_lds16(Kbase + (size_t)(jt0 * 64 + row) * E_DIM + gswc * 8,
                   Ks[0] + cc * 512);
        load_lds16(Vbase + (size_t)row * T_SEQ + jt0 * 64 + gswc * 8,
                   Vs[0] + cc * 512);
    }

    const float M8 = 8.0f * LOG2E;   // fixed max in exp2 domain

    for (int jt = jt0; jt < jt1; ++jt) {
        const int buf = (jt - jt0) & 1;
        __syncthreads();   // drains vmcnt -> buf ready; syncs buffer reuse
        if (jt + 1 < jt1) {
#pragma unroll
            for (int i = 0; i < 2; ++i) {
                int cc = w * 2 + i, row = cc * 8 + rloc;
                load_lds16(Kbase + (size_t)(jt + 1) * 64 * E_DIM
                           + (size_t)row * E_DIM + gswc * 8, Ks[buf ^ 1] + cc * 512);
                load_lds16(Vbase + (size_t)row * T_SEQ + (jt + 1) * 64 + gswc * 8,
                           Vs[buf ^ 1] + cc * 512);
            }
        }

        // S^T = K Q^T: tiles over t (nt). A=K-frag (m=t), B=aq (n=q).
        f32x4 sa[4];
#pragma unroll
        for (int nt = 0; nt < 4; ++nt) sa[nt] = zero;
        __builtin_amdgcn_s_setprio(1);
#pragma unroll
        for (int ks = 0; ks < 2; ++ks) {
            int cp = ((ks * 4 + quad) ^ sw) * 8;
#pragma unroll
            for (int nt = 0; nt < 4; ++nt) {
                bf16x8 bk = *(const bf16x8*)(Ks[buf] + (nt * 16 + l16) * 64 + cp);
                sa[nt] = __builtin_amdgcn_mfma_f32_16x16x32_bf16(bk, aq[ks], sa[nt], 0, 0, 0);
            }
        }
        __builtin_amdgcn_s_setprio(0);

        if (jt == qt) {   // causal mask: t > q (only split1's last tile)
#pragma unroll
            for (int nt = 0; nt < 4; ++nt)
#pragma unroll
                for (int r = 0; r < 4; ++r)
                    if (nt * 16 + quad * 4 + r > w * 16 + l16) sa[nt][r] = -1e30f;
        }

        // p = exp2(s - 8*log2e); pairwise l accumulation (short dep chains)
        bf16x4 bp[4];
        float lp[4];
#pragma unroll
        for (int nt = 0; nt < 4; ++nt) {
            float p0 = __builtin_amdgcn_exp2f(sa[nt][0] - M8);
            float p1 = __builtin_amdgcn_exp2f(sa[nt][1] - M8);
            float p2 = __builtin_amdgcn_exp2f(sa[nt][2] - M8);
            float p3 = __builtin_amdgcn_exp2f(sa[nt][3] - M8);
            bp[nt][0] = (short)f2bf_trunc(p0);
            bp[nt][1] = (short)f2bf_trunc(p1);
            bp[nt][2] = (short)f2bf_trunc(p2);
            bp[nt][3] = (short)f2bf_trunc(p3);
            lp[nt] = (p0 + p1) + (p2 + p3);
        }
        l_acc += (lp[0] + lp[1]) + (lp[2] + lp[3]);

        // O^T += V^T @ P^T : A = V^T rows d (from Vs), B = bp[kt] (k = t)
        __builtin_amdgcn_s_setprio(1);
#pragma unroll
        for (int kt = 0; kt < 4; ++kt) {
            const int tt = kt * 16 + quad * 4;          // t of this k-slice
            const int ch = tt >> 3, el = tt & 7;
#pragma unroll
            for (int dt = 0; dt < 4; ++dt) {
                const int vd = dt * 16 + l16;
                bf16x4 va = *(const bf16x4*)(Vs[buf] + vd * 64
                                             + ((ch ^ (vd & 7)) << 3) + el);
                o_acc[dt] = mfma16(va, bp[kt], o_acc[dt]);
            }
        }
        __builtin_amdgcn_s_setprio(0);
    }

    // Epilogue: reduce l across quads, store RAW f32 partials (no divide).
    l_acc += __shfl_xor(l_acc, 16);
    l_acc += __shfl_xor(l_acc, 32);
    float* Po = Pbuf + (((size_t)split << 22) | ((size_t)slot << 12));
    const int q = w * 16 + l16;
#pragma unroll
    for (int dt = 0; dt < 4; ++dt)
        *(f32x4*)(Po + q * 64 + dt * 16 + quad * 4) = o_acc[dt];
    if (quad == 0) Lbuf[(split << 16) | (slot << 6) | q] = l_acc;
}

// ---------------------------------------------------------------------------
// Output GEMM with FUSED split-K merge in the A-path. 128x128 tile, BK=32,
// 4 waves, double-buffered. A-staging is REG-STAGED (T14): issue f32 partial
// loads at the prefetch point, consume AFTER the MFMA block (latency hidden
// under compute), merge (P0+P1)*inv -> bf16 -> ds_write_b128 into the exact
// layout global_load_lds would have produced (base + c*512 + lane*8 ushorts).
// B-path (Wu) stays global_load_lds. Deletes attn_merge + the Ob round-trip.
// P layout: Pbuf[split][slot][q][d], slot=(b*16+h)*32+qt; l: Lbuf[split][slot][q].
// ---------------------------------------------------------------------------
__global__ __launch_bounds__(256) void gemm_o_m(
    const float* __restrict__ Pbuf, const float* __restrict__ Lbuf,
    const ushort* __restrict__ W, float* __restrict__ C)
{
    __shared__ ushort As[2 * 128 * 32];   // 16 KB
    __shared__ ushort Bs[2 * 128 * 32];   // 16 KB

    const int tid  = threadIdx.x;
    const int lane = tid & 63, w = tid >> 6;
    const int quad = lane >> 4, l16 = lane & 15;
    const int wm = w & 1, wn = w >> 1;
    const int m0 = blockIdx.y * 128, n0 = blockIdx.x * 128;

    const int rl   = lane >> 2;                       // row-in-chunk 0..15
    const int gsw  = (lane & 3) ^ ((lane >> 3) & 3);  // swizzled global chunk
    const int fsw  = (l16 >> 1) & 3;                  // frag-read xor factor

    // fixed per-thread A-source row geometry (2 chunks: c = ci*4 + w)
    int  qv[2], sb[2];
    bool h0[2];
#pragma unroll
    for (int ci = 0; ci < 2; ++ci) {
        const int token = m0 + (ci * 4 + w) * 16 + rl;
        const int qt = (token >> 6) & 31;
        qv[ci] = token & 63;
        sb[ci] = ((token >> 11) << 9) | qt;   // slot for h=0; slot = sb + (h<<5)
        h0[ci] = (qt > 0);                    // qt=0: split0 never ran
    }

    f32x4 p0a[2], p0b[2], p1a[2], p1b[2];
    float l0v[2], l1v[2];

    // issue A-source loads for k-cols [k0_, k0_+32) into registers
#define ISSUE_A(k0_) do {                                                     \
        const int e_  = (k0_) + gsw * 8;                                      \
        const int h_  = e_ >> 6, d0_ = e_ & 63;                               \
        _Pragma("unroll")                                                     \
        for (int ci = 0; ci < 2; ++ci) {                                      \
            const int slot_ = sb[ci] + (h_ << 5);                             \
            const float* p0_ = Pbuf + ((size_t)slot_ << 12) + qv[ci] * 64 + d0_; \
            const float* p1_ = p0_ + ((size_t)1 << 22);                       \
            p0a[ci] = *(const f32x4*)p0_;  p0b[ci] = *(const f32x4*)(p0_ + 4);\
            p1a[ci] = *(const f32x4*)p1_;  p1b[ci] = *(const f32x4*)(p1_ + 4);\
            l0v[ci] = Lbuf[(slot_ << 6) | qv[ci]];                            \
            l1v[ci] = Lbuf[(1 << 16) | (slot_ << 6) | qv[ci]];                \
        } } while (0)

    // merge + pack + ds_write into buffer buf_ (layout == gload_lds layout)
#define WRITE_A(buf_) do {                                                    \
        _Pragma("unroll")                                                     \
        for (int ci = 0; ci < 2; ++ci) {                                      \
            const int c_ = ci * 4 + w;                                        \
            const float inv_ = 1.0f / (l1v[ci] + (h0[ci] ? l0v[ci] : 0.f));   \
            bf16x8 vo;                                                        \
            _Pragma("unroll")                                                 \
            for (int j = 0; j < 4; ++j) {                                     \
                float a0 = p1a[ci][j] + (h0[ci] ? p0a[ci][j] : 0.f);          \
                float a1 = p1b[ci][j] + (h0[ci] ? p0b[ci][j] : 0.f);          \
                vo[j]     = (short)f2bf(a0 * inv_);                           \
                vo[4 + j] = (short)f2bf(a1 * inv_);                           \
            }                                                                 \
            *(bf16x8*)(As + (buf_) * 4096 + c_ * 512 + lane * 8) = vo;        \
        } } while (0)

    const f32x4 zero = {0.f, 0.f, 0.f, 0.f};
    f32x4 acc[4][4];
#pragma unroll
    for (int mt = 0; mt < 4; ++mt)
#pragma unroll
        for (int nt = 0; nt < 4; ++nt) acc[mt][nt] = zero;

    // prologue: A-regs + B-lds for k0=0 into buffer 0
    ISSUE_A(0);
#pragma unroll
    for (int i = 0; i < 2; ++i) {
        int c = i * 4 + w, row = c * 16 + rl;
        load_lds16(W + (size_t)(n0 + row) * E_DIM + gsw * 8, Bs + c * 512);
    }
    WRITE_A(0);

    for (int k0 = 0; k0 < E_DIM; k0 += 32) {
        const int buf = (k0 >> 5) & 1;
        const ushort* Ab = As + buf * 4096;
        const ushort* Bb = Bs + buf * 4096;
        __syncthreads();   // lgkm(ds_write)+vm(gload_lds) drained -> buf ready
        if (k0 + 32 < E_DIM) {
            ISSUE_A(k0 + 32);   // f32 loads in flight, consumed after MFMA
#pragma unroll
            for (int i = 0; i < 2; ++i) {
                int c = i * 4 + w, row = c * 16 + rl;
                load_lds16(W + (size_t)(n0 + row) * E_DIM + k0 + 32 + gsw * 8,
                           Bs + (buf ^ 1) * 4096 + c * 512);
            }
        }
        bf16x8 af[4], bfr[4];
#pragma unroll
        for (int mt = 0; mt < 4; ++mt)
            af[mt] = *(const bf16x8*)(Ab + (wm * 64 + mt * 16 + l16) * 32
                                      + ((quad ^ fsw) * 8));
#pragma unroll
        for (int nt = 0; nt < 4; ++nt)
            bfr[nt] = *(const bf16x8*)(Bb + (wn * 64 + nt * 16 + l16) * 32
                                       + ((quad ^ fsw) * 8));
#pragma unroll
        for (int mt = 0; mt < 4; ++mt)
#pragma unroll
            for (int nt = 0; nt < 4; ++nt)
                acc[mt][nt] = __builtin_amdgcn_mfma_f32_16x16x32_bf16(
                    af[mt], bfr[nt], acc[mt][nt], 0, 0, 0);
        if (k0 + 32 < E_DIM) WRITE_A(buf ^ 1);   // waitcnt auto; latency hidden
    }
#undef ISSUE_A
#undef WRITE_A

    const int row0 = m0 + wm * 64;
    const int col0 = n0 + wn * 64;
#pragma unroll
    for (int mt = 0; mt < 4; ++mt)
#pragma unroll
        for (int nt = 0; nt < 4; ++nt)
#pragma unroll
            for (int r = 0; r < 4; ++r)
                C[(size_t)(row0 + mt * 16 + quad * 4 + r) * E_DIM
                  + col0 + nt * 16 + l16] = acc[mt][nt][r];
}

// ---------------------------------------------------------------------------
extern "C" void kernel_launch(void* const* d_in, const int* in_sizes, int n_in,
                              void* d_out, int out_size, void* d_ws, size_t ws_size,
                              hipStream_t stream) {
    const float* x     = (const float*)d_in[0];
    const float* Wk    = (const float*)d_in[1];
    const float* Wq    = (const float*)d_in[2];
    const float* Wv    = (const float*)d_in[3];
    const float* Wu    = (const float*)d_in[4];
    const float* kln_w = (const float*)d_in[5];
    const float* kln_b = (const float*)d_in[6];
    const float* qln_w = (const float*)d_in[7];
    const float* qln_b = (const float*)d_in[8];
    float* out = (float*)d_out;

    const size_t NE = (size_t)M_ROWS * E_DIM;   // 4M elems
    const size_t NW = (size_t)E_DIM * E_DIM;    // 1M elems
    ushort* xb  = (ushort*)d_ws;                // 4M
    ushort* Wkb = xb  + NE;                     // 1M each
    ushort* Wqb = Wkb + NW;
    ushort* Wvb = Wqb + NW;
    ushort* Wub = Wvb + NW;
    ushort* Kb  = Wub + NW;                     // 4M
    ushort* Qb  = Kb  + NE;                     // 4M
    ushort* Vt  = Qb  + NE;                     // 4M, [bh][d][t]
    float*  Pbuf = (float*)(Vt + NE);           // 2 x 1024 x 4096 f32 = 32 MB
    float*  Lbuf = Pbuf + ((size_t)2 << 22);    // 2 x 65536 f32 = 512 KB

    // 1) fp32 -> bf16
    cvt_all<<<8192, 256, 0, stream>>>(x, Wk, Wq, Wv, Wu, xb, Wkb, Wqb, Wvb, Wub);

    // 2) K/Q/V projections (128x128 z-grid, dbuf) with fused LN + V-transpose
    gemm_qkv<<<dim3(E_DIM / 128, M_ROWS / 128, 3), 256, 0, stream>>>(
        xb, Wkb, Wqb, Wvb, Kb, Qb, Vt, kln_w, kln_b, qln_w, qln_b);

    // 3) Causal flash attention, split-K x2 (LPT) -> raw partials
    flash_attn6<<<2048, 256, 0, stream>>>(Qb, Kb, Vt, Pbuf, Lbuf);

    // 4) Output projection with fused split-K merge in A-path -> fp32 out
    gemm_o_m<<<dim3(E_DIM / 128, M_ROWS / 128), 256, 0, stream>>>(
        Pbuf, Lbuf, Wub, out);
}

// Round 8
// 182.859 us; speedup vs baseline: 1.1520x; 1.1520x over previous
//
#include <hip/hip_runtime.h>
#include <math.h>

// Problem constants (B=2, T=2048, E=1024, H=16, S=64)
#define T_SEQ 2048
#define E_DIM 1024
#define NH    16
#define HS    64
#define NB    2
#define M_ROWS 4096

typedef __attribute__((ext_vector_type(8))) short bf16x8;
typedef __attribute__((ext_vector_type(4))) short bf16x4;
typedef __attribute__((ext_vector_type(4))) float f32x4;

#define AS1 __attribute__((address_space(1)))
#define AS3 __attribute__((address_space(3)))

#define LOG2E 1.4426950408889634f

// 16x16x16 bf16 MFMA (K=16): B-operand k-index (quad*4+j) matches the
// C-layout row index (quad*4+r) — QK^T's S^T accumulator feeds PV directly.
__device__ __forceinline__ f32x4 mfma16(bf16x4 a, bf16x4 b, f32x4 c) {
    return __builtin_amdgcn_mfma_f32_16x16x16bf16_1k(a, b, c, 0, 0, 0);
}

__device__ __forceinline__ ushort f2bf(float f) {
    union { float f; unsigned u; } c; c.f = f;
    unsigned r = c.u + 0x7fffu + ((c.u >> 16) & 1u);
    return (ushort)(r >> 16);
}
__device__ __forceinline__ ushort f2bf_trunc(float f) {
    union { float f; unsigned u; } c; c.f = f;
    return (ushort)(c.u >> 16);
}

__device__ __forceinline__ void load_lds16(const ushort* g, ushort* l) {
    // 16B per lane, LDS dest = wave-uniform base + lane*16 (HW behavior)
    __builtin_amdgcn_global_load_lds((const AS1 unsigned int*)g,
                                     (AS3 unsigned int*)l, 16, 0, 0);
}

// ---------------------------------------------------------------------------
// fp32 -> bf16 conversion for x and the four weight matrices.
// ---------------------------------------------------------------------------
__global__ __launch_bounds__(256) void cvt_all(
    const float* __restrict__ x,  const float* __restrict__ Wk,
    const float* __restrict__ Wq, const float* __restrict__ Wv,
    const float* __restrict__ Wu,
    ushort* __restrict__ xb,  ushort* __restrict__ Wkb,
    ushort* __restrict__ Wqb, ushort* __restrict__ Wvb,
    ushort* __restrict__ Wub)
{
    int i4 = blockIdx.x * 256 + threadIdx.x;   // 0 .. 2M-1 (float4 units)
    int region = i4 >> 18;
    const float* src; ushort* dst; int off;
    if      (region < 4)  { src = x;  dst = xb;  off = i4; }
    else if (region == 4) { src = Wk; dst = Wkb; off = i4 - (4 << 18); }
    else if (region == 5) { src = Wq; dst = Wqb; off = i4 - (5 << 18); }
    else if (region == 6) { src = Wv; dst = Wvb; off = i4 - (6 << 18); }
    else                  { src = Wu; dst = Wub; off = i4 - (7 << 18); }
    float4 v = *(const float4*)(src + (size_t)off * 4);
    ushort4 o; o.x = f2bf(v.x); o.y = f2bf(v.y); o.z = f2bf(v.z); o.w = f2bf(v.w);
    *(ushort4*)(dst + (size_t)off * 4) = o;
}

// ---------------------------------------------------------------------------
// bf16 MFMA GEMM core, 128x128 tile, BK=32, 4 waves, double-buffered.
// 32 KB LDS -> 3 blocks/CU; inter-block overlap hides the per-tile drains.
// ---------------------------------------------------------------------------
__device__ __forceinline__ void gemm_core_db(
    const ushort* __restrict__ A, const ushort* __restrict__ W,
    int m0, int n0, ushort* As, ushort* Bs, f32x4 acc[4][4])
{
    const int tid  = threadIdx.x;
    const int lane = tid & 63, w = tid >> 6;
    const int quad = lane >> 4, l16 = lane & 15;
    const int wm = w & 1, wn = w >> 1;

    const int rl   = lane >> 2;                       // row-in-chunk 0..15
    const int gsw  = (lane & 3) ^ ((lane >> 3) & 3);  // swizzled global chunk
    const int fsw  = (l16 >> 1) & 3;                  // frag-read xor factor

    const f32x4 zero = {0.f, 0.f, 0.f, 0.f};
#pragma unroll
    for (int mt = 0; mt < 4; ++mt)
#pragma unroll
        for (int nt = 0; nt < 4; ++nt) acc[mt][nt] = zero;

    // initial stage into buffer 0
#pragma unroll
    for (int i = 0; i < 2; ++i) {
        int c = i * 4 + w;                 // chunk 0..7 (16 rows x 64B)
        int row = c * 16 + rl;
        load_lds16(A + (size_t)(m0 + row) * E_DIM + gsw * 8, As + c * 512);
        load_lds16(W + (size_t)(n0 + row) * E_DIM + gsw * 8, Bs + c * 512);
    }

    for (int k0 = 0; k0 < E_DIM; k0 += 32) {
        const int buf = (k0 >> 5) & 1;
        ushort* Ab = As + buf * 4096;
        ushort* Bb = Bs + buf * 4096;
        __syncthreads();   // own-wave vmcnt drained -> buf ready; syncs reuse
        if (k0 + 32 < E_DIM) {
            ushort* An = As + (buf ^ 1) * 4096;
            ushort* Bn = Bs + (buf ^ 1) * 4096;
#pragma unroll
            for (int i = 0; i < 2; ++i) {
                int c = i * 4 + w;
                int row = c * 16 + rl;
                load_lds16(A + (size_t)(m0 + row) * E_DIM + k0 + 32 + gsw * 8,
                           An + c * 512);
                load_lds16(W + (size_t)(n0 + row) * E_DIM + k0 + 32 + gsw * 8,
                           Bn + c * 512);
            }
        }
        bf16x8 af[4], bfr[4];
#pragma unroll
        for (int mt = 0; mt < 4; ++mt)
            af[mt] = *(const bf16x8*)(Ab + (wm * 64 + mt * 16 + l16) * 32
                                      + ((quad ^ fsw) * 8));
#pragma unroll
        for (int nt = 0; nt < 4; ++nt)
            bfr[nt] = *(const bf16x8*)(Bb + (wn * 64 + nt * 16 + l16) * 32
                                       + ((quad ^ fsw) * 8));
#pragma unroll
        for (int mt = 0; mt < 4; ++mt)
#pragma unroll
            for (int nt = 0; nt < 4; ++nt)
                acc[mt][nt] = __builtin_amdgcn_mfma_f32_16x16x32_bf16(
                    af[mt], bfr[nt], acc[mt][nt], 0, 0, 0);
    }
}

// ---------------------------------------------------------------------------
// QKV GEMM with fused epilogues, XCD-CHUNKED placement (1-D grid 768):
// XCD k owns m-bands [4k, 4k+4) for all n and all z -> per-XCD A working set
// = 4 x 256 KB = 1 MB, resident in that XCD's 4 MB L2 across the whole K-loop
// (weights stream through L3, shared by all XCDs). Default round-robin had
// the 8 blocks sharing an A-band on 8 DIFFERENT XCDs -> no L2 reuse.
//  z=0: K -> LN(kln) -> Kb ; z=1: Q -> LN(qln)*0.125*log2e -> Qb
//  z=2: V -> transposed store -> Vt [bh][d][t]
// ---------------------------------------------------------------------------
__global__ __launch_bounds__(256) void gemm_qkv(
    const ushort* __restrict__ A,
    const ushort* __restrict__ W0, const ushort* __restrict__ W1,
    const ushort* __restrict__ W2,
    ushort* __restrict__ Kb, ushort* __restrict__ Qb, ushort* __restrict__ Vt,
    const float* __restrict__ kw, const float* __restrict__ kbias,
    const float* __restrict__ qw, const float* __restrict__ qbias)
{
    __shared__ ushort As[2 * 128 * 32];   // 16 KB
    __shared__ ushort Bs[2 * 128 * 32];   // 16 KB

    const int lid = blockIdx.x;            // 0..767
    const int xcd = lid & 7;               // wgid%8 ~ XCD (round-robin)
    const int idx = lid >> 3;              // 0..95 within XCD
    const int z   = idx >> 5;              // 0..2
    const int rem = idx & 31;
    const int m0  = (xcd * 4 + (rem >> 3)) * 128;   // 4 m-bands per XCD
    const int n0  = (rem & 7) * 128;

    const ushort* W = (z == 0) ? W0 : (z == 1) ? W1 : W2;
    f32x4 acc[4][4];
    gemm_core_db(A, W, m0, n0, As, Bs, acc);

    const int lane = threadIdx.x & 63, w = threadIdx.x >> 6;
    const int quad = lane >> 4, l16 = lane & 15;
    const int wm = w & 1, wn = w >> 1;
    const int row0 = m0 + wm * 64;
    const int col0 = n0 + wn * 64;

    if (z < 2) {
        ushort* C = z ? Qb : Kb;
        const float* lw = z ? qw : kw;
        const float* lb = z ? qbias : kbias;
        const float scale = z ? (0.125f * LOG2E) : 1.0f;
        float wv[4], bv_[4];
#pragma unroll
        for (int nt = 0; nt < 4; ++nt) {
            wv[nt]  = lw[nt * 16 + l16];
            bv_[nt] = lb[nt * 16 + l16];
        }
#pragma unroll
        for (int mt = 0; mt < 4; ++mt)
#pragma unroll
            for (int r = 0; r < 4; ++r) {
                float v[4], d[4];
#pragma unroll
                for (int nt = 0; nt < 4; ++nt) v[nt] = acc[mt][nt][r];
                float s = v[0] + v[1] + v[2] + v[3];
                s += __shfl_xor(s, 1); s += __shfl_xor(s, 2);
                s += __shfl_xor(s, 4); s += __shfl_xor(s, 8);
                float mu = s * (1.0f / 64.0f);
                float q2 = 0.f;
#pragma unroll
                for (int nt = 0; nt < 4; ++nt) { d[nt] = v[nt] - mu; q2 += d[nt] * d[nt]; }
                q2 += __shfl_xor(q2, 1); q2 += __shfl_xor(q2, 2);
                q2 += __shfl_xor(q2, 4); q2 += __shfl_xor(q2, 8);
                float rin = rsqrtf(q2 * (1.0f / 64.0f) + 1e-5f);
                int row = row0 + mt * 16 + quad * 4 + r;
#pragma unroll
                for (int nt = 0; nt < 4; ++nt)
                    C[(size_t)row * E_DIM + col0 + nt * 16 + l16] =
                        f2bf((d[nt] * rin * wv[nt] + bv_[nt]) * scale);
            }
    } else {
        // V: transposed store Vt[(b*NH+h)*64 + d][t]
        const int bidx = m0 >> 11;
        const int hh   = col0 >> 6;
        const int t0   = (m0 & 2047) + wm * 64;
#pragma unroll
        for (int mt = 0; mt < 4; ++mt)
#pragma unroll
            for (int nt = 0; nt < 4; ++nt) {
                ushort4 pk = make_ushort4(f2bf(acc[mt][nt][0]), f2bf(acc[mt][nt][1]),
                                          f2bf(acc[mt][nt][2]), f2bf(acc[mt][nt][3]));
                size_t off = ((size_t)(bidx * NH + hh) * 64 + nt * 16 + l16) * T_SEQ
                             + t0 + mt * 16 + quad * 4;
                *(ushort4*)(Vt + off) = pk;
            }
    }
}

// ---------------------------------------------------------------------------
// Output GEMM, XCD-chunked (1-D grid 256): XCD k owns m-bands [4k,4k+4) ->
// per-XCD working set A 1 MB + Wu 2 MB = 3 MB < 4 MB L2. fp32 store.
// ---------------------------------------------------------------------------
__global__ __launch_bounds__(256) void gemm_o(
    const ushort* __restrict__ A, const ushort* __restrict__ W,
    float* __restrict__ C)
{
    __shared__ ushort As[2 * 128 * 32];
    __shared__ ushort Bs[2 * 128 * 32];

    const int lid = blockIdx.x;            // 0..255
    const int idx = lid >> 3;              // 0..31
    const int m0  = ((lid & 7) * 4 + (idx >> 3)) * 128;
    const int n0  = (idx & 7) * 128;

    f32x4 acc[4][4];
    gemm_core_db(A, W, m0, n0, As, Bs, acc);

    const int lane = threadIdx.x & 63, w = threadIdx.x >> 6;
    const int quad = lane >> 4, l16 = lane & 15;
    const int row0 = m0 + (w & 1) * 64;
    const int col0 = n0 + (w >> 1) * 64;
#pragma unroll
    for (int mt = 0; mt < 4; ++mt)
#pragma unroll
        for (int nt = 0; nt < 4; ++nt)
#pragma unroll
            for (int r = 0; r < 4; ++r)
                C[(size_t)(row0 + mt * 16 + quad * 4 + r) * E_DIM
                  + col0 + nt * 16 + l16] = acc[mt][nt][r];
}

// ---------------------------------------------------------------------------
// Flash attention v5 (causal, bf16 MFMA, exp2 fixed-max softmax,
// register-direct PV via S^T). XCD-CHUNKED bh placement: XCD k owns
// bh in [4k, 4k+4) -> its K+V working set = 4 x 512 KB = 2 MB, L2-resident
// and shared by all 128 resident blocks of that XCD. Per-CU balance scheme
// unchanged from the proven round-0 swizzle: CU slot c gets qt in
// {q0, 15-q0, 16+q0, 31-q0} over the 4 rounds (sum of iters = 66 per CU).
// ---------------------------------------------------------------------------
__global__ __launch_bounds__(256, 4) void flash_attn5(
    const ushort* __restrict__ Qg, const ushort* __restrict__ Kg,
    const ushort* __restrict__ Vt, ushort* __restrict__ O)
{
    __shared__ ushort Ks[2][64 * 64];   // 16 KB
    __shared__ ushort Vs[2][64 * 64];   // 16 KB

    const int tid  = threadIdx.x;
    const int lane = tid & 63, w = tid >> 6;
    const int quad = lane >> 4, l16 = lane & 15;

    const int L   = blockIdx.x;         // 0..1023
    const int xcd = L & 7;              // wgid%8 ~ XCD (round-robin)
    const int idx = L >> 3;             // 0..127 within XCD
    const int c   = idx & 31;           // CU slot within XCD
    const int r   = idx >> 5;           // dispatch round 0..3
    const int q0  = c >> 2;             // 0..7
    const int bh  = xcd * 4 + (c & 3);  // 4 bh per XCD -> K/V L2-resident
    const int qt  = (r == 0) ? q0 : (r == 1) ? (15 - q0)
                  : (r == 2) ? (16 + q0) : (31 - q0);
    const int b = bh >> 4, h = bh & 15;

    const ushort* Qbase = Qg + ((size_t)b * T_SEQ) * E_DIM + h * HS;
    const ushort* Kbase = Kg + ((size_t)b * T_SEQ) * E_DIM + h * HS;
    const ushort* Vbase = Vt + ((size_t)bh * HS) * T_SEQ;   // [d][t]

    const int rloc = lane >> 3;
    const int gswc = (lane & 7) ^ rloc;     // swizzled global chunk (staging)
    const int sw   = l16 & 7;               // frag-read xor factor

    // Q B-frags (16x16x32): B[n=q][k=d], lane n=l16 -> q row, k=quad*8+j
    bf16x8 aq[2];
#pragma unroll
    for (int ks = 0; ks < 2; ++ks)
        aq[ks] = *(const bf16x8*)(Qbase + (size_t)(qt * 64 + w * 16 + l16) * E_DIM
                                  + ks * 32 + quad * 8);

    const f32x4 zero = {0.f, 0.f, 0.f, 0.f};
    f32x4 o_acc[4];                     // O^T: lane col=q(l16), rows d=quad*4+r
#pragma unroll
    for (int dt = 0; dt < 4; ++dt) o_acc[dt] = zero;
    float l_acc = 0.f;                  // q is lane-fixed -> scalar l

    // initial stage into buffer 0
#pragma unroll
    for (int i = 0; i < 2; ++i) {
        int cc = w * 2 + i, row = cc * 8 + rloc;
        load_lds16(Kbase + (size_t)row * E_DIM + gswc * 8, Ks[0] + cc * 512);
        load_lds16(Vbase + (size_t)row * T_SEQ + gswc * 8, Vs[0] + cc * 512);
    }

    const float M8 = 8.0f * LOG2E;   // fixed max in exp2 domain

    for (int jt = 0; jt <= qt; ++jt) {
        const int buf = jt & 1;
        __syncthreads();   // drains vmcnt -> buf ready; syncs buffer reuse
        if (jt < qt) {
#pragma unroll
            for (int i = 0; i < 2; ++i) {
                int cc = w * 2 + i, row = cc * 8 + rloc;
                load_lds16(Kbase + (size_t)(jt + 1) * 64 * E_DIM
                           + (size_t)row * E_DIM + gswc * 8, Ks[buf ^ 1] + cc * 512);
                load_lds16(Vbase + (size_t)row * T_SEQ + (jt + 1) * 64 + gswc * 8,
                           Vs[buf ^ 1] + cc * 512);
            }
        }

        // S^T = K Q^T: tiles over t (nt). A=K-frag (m=t), B=aq (n=q).
        f32x4 sa[4];
#pragma unroll
        for (int nt = 0; nt < 4; ++nt) sa[nt] = zero;
#pragma unroll
        for (int ks = 0; ks < 2; ++ks) {
            int cp = ((ks * 4 + quad) ^ sw) * 8;
#pragma unroll
            for (int nt = 0; nt < 4; ++nt) {
                bf16x8 bk = *(const bf16x8*)(Ks[buf] + (nt * 16 + l16) * 64 + cp);
                sa[nt] = __builtin_amdgcn_mfma_f32_16x16x32_bf16(bk, aq[ks], sa[nt], 0, 0, 0);
            }
        }

        if (jt == qt) {   // causal mask: t > q  (tile-local coords, same origin)
#pragma unroll
            for (int nt = 0; nt < 4; ++nt)
#pragma unroll
                for (int r2 = 0; r2 < 4; ++r2)
                    if (nt * 16 + quad * 4 + r2 > w * 16 + l16) sa[nt][r2] = -1e30f;
        }

        // p = exp2(s - 8*log2e); scalar l accumulation; pack B-frags (trunc)
        bf16x4 bp[4];
#pragma unroll
        for (int nt = 0; nt < 4; ++nt)
#pragma unroll
            for (int r2 = 0; r2 < 4; ++r2) {
                float p = __builtin_amdgcn_exp2f(sa[nt][r2] - M8);
                l_acc += p;
                bp[nt][r2] = (short)f2bf_trunc(p);
            }

        // O^T += V^T @ P^T : A = V^T rows d (from Vs), B = bp[kt] (k = t)
#pragma unroll
        for (int kt = 0; kt < 4; ++kt) {
            const int tt = kt * 16 + quad * 4;          // t of this k-slice
            const int ch = tt >> 3, el = tt & 7;
#pragma unroll
            for (int dt = 0; dt < 4; ++dt) {
                const int vd = dt * 16 + l16;
                bf16x4 va = *(const bf16x4*)(Vs[buf] + vd * 64
                                             + ((ch ^ (vd & 7)) << 3) + el);
                o_acc[dt] = mfma16(va, bp[kt], o_acc[dt]);
            }
        }
    }

    // Epilogue: l reduce across quads (q = l16 fixed), divide, pack, store.
    l_acc += __shfl_xor(l_acc, 16);
    l_acc += __shfl_xor(l_acc, 32);
    const float inv = 1.0f / l_acc;
    const int trow = qt * 64 + w * 16 + l16;
#pragma unroll
    for (int dt = 0; dt < 4; ++dt) {
        ushort4 pk = make_ushort4(f2bf(o_acc[dt][0] * inv), f2bf(o_acc[dt][1] * inv),
                                  f2bf(o_acc[dt][2] * inv), f2bf(o_acc[dt][3] * inv));
        *(ushort4*)(O + ((size_t)b * T_SEQ + trow) * E_DIM + h * HS
                    + dt * 16 + quad * 4) = pk;
    }
}

// ---------------------------------------------------------------------------
extern "C" void kernel_launch(void* const* d_in, const int* in_sizes, int n_in,
                              void* d_out, int out_size, void* d_ws, size_t ws_size,
                              hipStream_t stream) {
    const float* x     = (const float*)d_in[0];
    const float* Wk    = (const float*)d_in[1];
    const float* Wq    = (const float*)d_in[2];
    const float* Wv    = (const float*)d_in[3];
    const float* Wu    = (const float*)d_in[4];
    const float* kln_w = (const float*)d_in[5];
    const float* kln_b = (const float*)d_in[6];
    const float* qln_w = (const float*)d_in[7];
    const float* qln_b = (const float*)d_in[8];
    float* out = (float*)d_out;

    const size_t NE = (size_t)M_ROWS * E_DIM;   // 4M elems
    const size_t NW = (size_t)E_DIM * E_DIM;    // 1M elems
    ushort* xb  = (ushort*)d_ws;                // 4M
    ushort* Wkb = xb  + NE;                     // 1M each
    ushort* Wqb = Wkb + NW;
    ushort* Wvb = Wqb + NW;
    ushort* Wub = Wvb + NW;
    ushort* Kb  = Wub + NW;                     // 4M
    ushort* Qb  = Kb  + NE;                     // 4M
    ushort* Vt  = Qb  + NE;                     // 4M, [bh][d][t]
    ushort* Ob  = Vt  + NE;                     // 4M

    // 1) fp32 -> bf16
    cvt_all<<<8192, 256, 0, stream>>>(x, Wk, Wq, Wv, Wu, xb, Wkb, Wqb, Wvb, Wub);

    // 2) K/Q/V projections (128x128, dbuf) with fused LN + V-transpose,
    //    XCD-chunked m-band placement
    gemm_qkv<<<768, 256, 0, stream>>>(
        xb, Wkb, Wqb, Wvb, Kb, Qb, Vt, kln_w, kln_b, qln_w, qln_b);

    // 3) Causal flash attention (register-direct PV), XCD-chunked bh placement
    flash_attn5<<<1024, 256, 0, stream>>>(Qb, Kb, Vt, Ob);

    // 4) Output projection (128x128, dbuf), XCD-chunked -> fp32 out
    gemm_o<<<256, 256, 0, stream>>>(Ob, Wub, out);
}